// Round 1
// baseline (3563.750 us; speedup 1.0000x reference)
//
#include <hip/hip_runtime.h>
#include <hip/hip_bf16.h>

#define K_CODES 8192
#define DIM     512
#define N_VEC   32768

// ---------------------------------------------------------------------------
// Kernel A: row norms. rows [0,N_VEC) -> x2 from z; rows [N_VEC, N_VEC+K) -> e2
// One wave per row: 64 lanes x 8 floats = 512.
// ---------------------------------------------------------------------------
__global__ __launch_bounds__(256) void vq_norms(const float* __restrict__ z,
                                                const float* __restrict__ cb,
                                                float* __restrict__ x2,
                                                float* __restrict__ e2) {
    int wave = threadIdx.x >> 6;
    int lane = threadIdx.x & 63;
    int row  = blockIdx.x * 4 + wave;
    const float* src;
    float* dst;
    if (row < N_VEC) {
        src = z + (size_t)row * DIM;
        dst = x2 + row;
    } else {
        src = cb + (size_t)(row - N_VEC) * DIM;
        dst = e2 + (row - N_VEC);
    }
    const float4* s4 = (const float4*)src;
    float4 v0 = s4[lane * 2];
    float4 v1 = s4[lane * 2 + 1];
    float s = v0.x * v0.x + v0.y * v0.y + v0.z * v0.z + v0.w * v0.w +
              v1.x * v1.x + v1.y * v1.y + v1.z * v1.z + v1.w * v1.w;
#pragma unroll
    for (int off = 32; off >= 1; off >>= 1) s += __shfl_xor(s, off, 64);
    if (lane == 0) *dst = s;
}

// ---------------------------------------------------------------------------
// Kernel B: fused distance + argmin + z_q gather + loss/histogram.
// Tile: 64 rows x 256 codes, depth chunks of 32. 256 threads, 8x8 micro-tile.
// dist(r,k) = e2[k] - 2 * dot(x_r, e_k)   (x2 added only for the loss scalar)
// ---------------------------------------------------------------------------
#define BM 64
#define BK 256
#define BD 32

__global__ __launch_bounds__(256, 2) void vq_main(
    const float* __restrict__ z, const float* __restrict__ cb,
    const float* __restrict__ x2, const float* __restrict__ e2,
    float* __restrict__ zq, float* __restrict__ idxf,
    float* __restrict__ counts, float* __restrict__ lossAcc) {
    __shared__ float As[BD][BM];   // 8 KB, transposed: As[d][row]
    __shared__ float Bs[BD][BK];   // 32 KB, transposed: Bs[d][code]
    __shared__ int   sIdx[BM];

    const int tid = threadIdx.x;
    const int tx  = tid & 31;   // code group: codes tx*8 .. tx*8+7 (permuted by sw)
    const int ty  = tid >> 5;   // row group:  rows  ty*8 .. ty*8+7
    const int rowBase = blockIdx.x * BM;

    // bank-conflict half-swap: threads with (tx&8) load their upper float4 first.
    const int sw = (tx & 8) ? 4 : 0;

    float best[8];
    int   bidx[8];
#pragma unroll
    for (int i = 0; i < 8; ++i) { best[i] = 3.4e38f; bidx[i] = K_CODES; }

    // staging assignment for As: thread -> (row = tid>>2, 8-float quarter = tid&3)
    const int sRow = tid >> 2;
    const int sQ   = tid & 3;

    for (int kt = 0; kt < K_CODES; kt += BK) {
        float acc[8][8];
#pragma unroll
        for (int i = 0; i < 8; ++i)
#pragma unroll
            for (int j = 0; j < 8; ++j) acc[i][j] = 0.0f;

        for (int dc = 0; dc < DIM; dc += BD) {
            __syncthreads();   // previous-iteration readers done before overwrite
            // --- stage A tile (64 rows x 32 d), transposed ---
            {
                const float* srcA = z + (size_t)(rowBase + sRow) * DIM + dc + sQ * 8;
                float4 va0 = ((const float4*)srcA)[0];
                float4 va1 = ((const float4*)srcA)[1];
                int c0 = sQ * 8;
                As[c0 + 0][sRow] = va0.x; As[c0 + 1][sRow] = va0.y;
                As[c0 + 2][sRow] = va0.z; As[c0 + 3][sRow] = va0.w;
                As[c0 + 4][sRow] = va1.x; As[c0 + 5][sRow] = va1.y;
                As[c0 + 6][sRow] = va1.z; As[c0 + 7][sRow] = va1.w;
            }
            // --- stage B tile (256 codes x 32 d), transposed; thread = code ---
            {
                const float4* srcB = (const float4*)(cb + (size_t)(kt + tid) * DIM + dc);
#pragma unroll
                for (int j = 0; j < 8; ++j) {
                    float4 v = srcB[j];
                    Bs[j * 4 + 0][tid] = v.x; Bs[j * 4 + 1][tid] = v.y;
                    Bs[j * 4 + 2][tid] = v.z; Bs[j * 4 + 3][tid] = v.w;
                }
            }
            __syncthreads();

#pragma unroll
            for (int d = 0; d < BD; ++d) {
                float a[8], b[8];
                *(float4*)&a[0] = *(const float4*)&As[d][ty * 8];
                *(float4*)&a[4] = *(const float4*)&As[d][ty * 8 + 4];
                // b[0..3] holds codes sw..sw+3, b[4..7] holds codes (sw^4)..(sw^4)+3
                *(float4*)&b[0] = *(const float4*)&Bs[d][tx * 8 + sw];
                *(float4*)&b[4] = *(const float4*)&Bs[d][tx * 8 + (sw ^ 4)];
#pragma unroll
                for (int i = 0; i < 8; ++i)
#pragma unroll
                    for (int j = 0; j < 8; ++j) acc[i][j] += a[i] * b[j];
            }
        }

        // per-ktile argmin update (code index accounts for the sw permutation;
        // explicit tie-break keeps the LOWEST index like jnp.argmin)
#pragma unroll
        for (int j = 0; j < 8; ++j) {
            int code = kt + tx * 8 + ((j < 4) ? (sw + j) : ((sw ^ 4) + j - 4));
            float ev = e2[code];
#pragma unroll
            for (int i = 0; i < 8; ++i) {
                float dist = ev - 2.0f * acc[i][j];
                if (dist < best[i] || (dist == best[i] && code < bidx[i])) {
                    best[i] = dist;
                    bidx[i] = code;
                }
            }
        }
    }

    // reduce argmin across the 32 tx-lanes sharing each row group
#pragma unroll
    for (int off = 16; off >= 1; off >>= 1) {
#pragma unroll
        for (int i = 0; i < 8; ++i) {
            float od = __shfl_xor(best[i], off, 64);
            int   oi = __shfl_xor(bidx[i], off, 64);
            if (od < best[i] || (od == best[i] && oi < bidx[i])) {
                best[i] = od;
                bidx[i] = oi;
            }
        }
    }

    if (tx == 0) {
        float lsum = 0.0f;
#pragma unroll
        for (int i = 0; i < 8; ++i) {
            int row = ty * 8 + i;
            sIdx[row] = bidx[i];
            idxf[rowBase + row] = (float)bidx[i];
            atomicAdd(&counts[bidx[i]], 1.0f);
            lsum += x2[rowBase + row] + best[i];   // = ||x - e||^2
        }
        atomicAdd(lossAcc, lsum);
    }
    __syncthreads();

    // gather z_q = codebook[best] for this block's 64 rows (coalesced float4)
    const float4* cb4 = (const float4*)cb;
    float4* zq4 = (float4*)(zq + (size_t)rowBase * DIM);
    for (int t = tid; t < BM * (DIM / 4); t += 256) {
        int row = t >> 7;          // DIM/4 = 128 float4 per row
        int f4  = t & 127;
        zq4[(size_t)row * 128 + f4] = cb4[(size_t)sIdx[row] * 128 + f4];
    }
}

// ---------------------------------------------------------------------------
// Kernel C: finalize scalars (vq_loss, perplexity)
// ---------------------------------------------------------------------------
__global__ __launch_bounds__(256) void vq_finalize(const float* __restrict__ counts,
                                                   const float* __restrict__ lossAcc,
                                                   float* __restrict__ out_loss,
                                                   float* __restrict__ out_perp) {
    __shared__ float wsum[4];
    int tid = threadIdx.x;
    float s = 0.0f;
    for (int i = tid; i < K_CODES; i += 256) {
        float p = counts[i] * (1.0f / (float)N_VEC);
        s += p * logf(p + 1e-10f);
    }
#pragma unroll
    for (int off = 32; off >= 1; off >>= 1) s += __shfl_xor(s, off, 64);
    if ((tid & 63) == 0) wsum[tid >> 6] = s;
    __syncthreads();
    if (tid == 0) {
        float tot = wsum[0] + wsum[1] + wsum[2] + wsum[3];
        *out_perp = expf(-tot);
        // vq_loss = (1 + BETA) * mean((z_q - z)^2), BETA = 0.25
        *out_loss = 1.25f * lossAcc[0] / (float)(N_VEC * DIM);
    }
}

// ---------------------------------------------------------------------------
extern "C" void kernel_launch(void* const* d_in, const int* in_sizes, int n_in,
                              void* d_out, int out_size, void* d_ws, size_t ws_size,
                              hipStream_t stream) {
    (void)in_sizes; (void)n_in; (void)out_size; (void)ws_size;
    const float* z  = (const float*)d_in[0];
    const float* cb = (const float*)d_in[1];

    float* ws      = (float*)d_ws;
    float* x2      = ws;                 // 32768
    float* e2      = ws + 32768;         // 8192
    float* counts  = ws + 40960;         // 8192
    float* lossAcc = ws + 49152;         // 1

    float* out      = (float*)d_out;
    float* zq       = out;                        // 8*4096*512
    float* out_loss = out + 16777216;             // 1
    float* idxf     = out + 16777217;             // 32768 (indices as float)
    float* out_perp = out + 16777217 + 32768;     // 1

    hipMemsetAsync(counts, 0, (K_CODES + 1) * sizeof(float), stream);
    vq_norms<<<(N_VEC + K_CODES) / 4, 256, 0, stream>>>(z, cb, x2, e2);
    vq_main<<<N_VEC / BM, 256, 0, stream>>>(z, cb, x2, e2, zq, idxf, counts, lossAcc);
    vq_finalize<<<1, 256, 0, stream>>>(counts, lossAcc, out_loss, out_perp);
}